// Round 1
// baseline (171.878 us; speedup 1.0000x reference)
//
#include <hip/hip_runtime.h>
#include <math.h>

constexpr int N_LOC    = 100000;
constexpr int D_IN     = 128;
constexpr int N_ROUTES = 8192;
constexpr int ROUTE_LEN = 100;
constexpr int D_OUT    = 256;
constexpr float LN_EPS = 1e-5f;

constexpr int RPB      = 8;    // routes per block
constexpr int NTHREADS = 256;  // == D_OUT

__global__ __launch_bounds__(NTHREADS, 4)
void routes_encoder_kernel(const float* __restrict__ emb,    // [N_LOC, D_IN]
                           const int*   __restrict__ idx,    // [N_ROUTES, ROUTE_LEN]
                           const float* __restrict__ W,      // [D_IN, D_OUT]
                           const float* __restrict__ bias,   // [D_OUT]
                           const float* __restrict__ gamma,  // [D_OUT]
                           const float* __restrict__ beta,   // [D_OUT]
                           float* __restrict__ out)          // [N_ROUTES, D_OUT]
{
    __shared__ int   s_idx[RPB * ROUTE_LEN];
    __shared__ float s_pooled[RPB][D_IN];
    __shared__ float s_sum[4][RPB];
    __shared__ float s_ssq[4][RPB];

    const int tid    = threadIdx.x;
    const int route0 = blockIdx.x * RPB;

    // ---- 1. stage indices (coalesced) ----
    for (int i = tid; i < RPB * ROUTE_LEN; i += NTHREADS)
        s_idx[i] = idx[(size_t)route0 * ROUTE_LEN + i];
    __syncthreads();

    // ---- 2. gather + max-pool: 32-thread group g owns route g ----
    {
        const int g  = tid >> 5;   // 0..7
        const int d4 = tid & 31;   // float4 slot: dims 4*d4 .. 4*d4+3
        const int* gi = &s_idx[g * ROUTE_LEN];
        float4 m = make_float4(-INFINITY, -INFINITY, -INFINITY, -INFINITY);
        #pragma unroll 4
        for (int l = 0; l < ROUTE_LEN; ++l) {
            const float4 v = *reinterpret_cast<const float4*>(
                emb + (size_t)gi[l] * D_IN + d4 * 4);
            m.x = fmaxf(m.x, v.x);
            m.y = fmaxf(m.y, v.y);
            m.z = fmaxf(m.z, v.z);
            m.w = fmaxf(m.w, v.w);
        }
        *reinterpret_cast<float4*>(&s_pooled[g][d4 * 4]) = m;
    }
    __syncthreads();

    // ---- 3. GEMM + bias: thread tid computes output column tid for all RPB routes ----
    float h[RPB];
    {
        const float bo = bias[tid];
        #pragma unroll
        for (int r = 0; r < RPB; ++r) h[r] = bo;

        #pragma unroll 8
        for (int k = 0; k < D_IN; k += 4) {
            const float wk0 = W[(size_t)(k + 0) * D_OUT + tid];
            const float wk1 = W[(size_t)(k + 1) * D_OUT + tid];
            const float wk2 = W[(size_t)(k + 2) * D_OUT + tid];
            const float wk3 = W[(size_t)(k + 3) * D_OUT + tid];
            #pragma unroll
            for (int r = 0; r < RPB; ++r) {
                const float4 p = *reinterpret_cast<const float4*>(&s_pooled[r][k]);
                h[r] = fmaf(p.x, wk0, h[r]);
                h[r] = fmaf(p.y, wk1, h[r]);
                h[r] = fmaf(p.z, wk2, h[r]);
                h[r] = fmaf(p.w, wk3, h[r]);
            }
        }
    }

    // ---- 4. LayerNorm (E[x^2]-mu^2) + ReLU ----
    float s[RPB], ss[RPB];
    #pragma unroll
    for (int r = 0; r < RPB; ++r) { s[r] = h[r]; ss[r] = h[r] * h[r]; }

    #pragma unroll
    for (int off = 32; off > 0; off >>= 1) {
        #pragma unroll
        for (int r = 0; r < RPB; ++r) {
            s[r]  += __shfl_down(s[r],  off);
            ss[r] += __shfl_down(ss[r], off);
        }
    }
    const int wave = tid >> 6;
    if ((tid & 63) == 0) {
        #pragma unroll
        for (int r = 0; r < RPB; ++r) { s_sum[wave][r] = s[r]; s_ssq[wave][r] = ss[r]; }
    }
    __syncthreads();

    const float gm = gamma[tid];
    const float bt = beta[tid];
    #pragma unroll
    for (int r = 0; r < RPB; ++r) {
        const float tot = s_sum[0][r] + s_sum[1][r] + s_sum[2][r] + s_sum[3][r];
        const float tsq = s_ssq[0][r] + s_ssq[1][r] + s_ssq[2][r] + s_ssq[3][r];
        const float mu  = tot * (1.0f / D_OUT);
        const float var = tsq * (1.0f / D_OUT) - mu * mu;
        const float inv = rsqrtf(var + LN_EPS);
        const float y   = (h[r] - mu) * inv * gm + bt;
        out[(size_t)(route0 + r) * D_OUT + tid] = fmaxf(y, 0.0f);
    }
}

extern "C" void kernel_launch(void* const* d_in, const int* in_sizes, int n_in,
                              void* d_out, int out_size, void* d_ws, size_t ws_size,
                              hipStream_t stream) {
    const float* emb   = (const float*)d_in[0];
    const int*   idx   = (const int*)  d_in[1];
    const float* W     = (const float*)d_in[2];
    const float* bias  = (const float*)d_in[3];
    const float* gamma = (const float*)d_in[4];
    const float* beta  = (const float*)d_in[5];
    float* out = (float*)d_out;

    routes_encoder_kernel<<<dim3(N_ROUTES / RPB), dim3(NTHREADS), 0, stream>>>(
        emb, idx, W, bias, gamma, beta, out);
}

// Round 2
// 147.625 us; speedup vs baseline: 1.1643x; 1.1643x over previous
//
#include <hip/hip_runtime.h>
#include <math.h>

constexpr int N_LOC     = 100000;
constexpr int D_IN      = 128;
constexpr int N_ROUTES  = 8192;
constexpr int ROUTE_LEN = 100;
constexpr int D_OUT     = 256;
constexpr float LN_EPS  = 1e-5f;

constexpr int RPB      = 4;    // routes per block -> 2048 blocks = 8 blocks/CU
constexpr int NTHREADS = 256;  // == D_OUT

__global__ __launch_bounds__(NTHREADS, 8)   // 8 waves/SIMD -> 8 blocks/CU, caps VGPR at 64
void routes_encoder_kernel(const float* __restrict__ emb,    // [N_LOC, D_IN]
                           const int*   __restrict__ idx,    // [N_ROUTES, ROUTE_LEN]
                           const float* __restrict__ W,      // [D_IN, D_OUT]
                           const float* __restrict__ bias,   // [D_OUT]
                           const float* __restrict__ gamma,  // [D_OUT]
                           const float* __restrict__ beta,   // [D_OUT]
                           float* __restrict__ out)          // [N_ROUTES, D_OUT]
{
    __shared__ int   s_idx[RPB * ROUTE_LEN];   // 1600 B
    __shared__ float s_pooled[RPB][D_IN];      // 2048 B
    __shared__ float s_sum[4][RPB];
    __shared__ float s_ssq[4][RPB];

    const int tid    = threadIdx.x;
    const int route0 = blockIdx.x * RPB;

    // ---- 1. stage indices (coalesced) ----
    for (int i = tid; i < RPB * ROUTE_LEN; i += NTHREADS)
        s_idx[i] = idx[(size_t)route0 * ROUTE_LEN + i];
    __syncthreads();

    // ---- 2. gather + max-pool: wave w owns route w; lane owns a float2 slice ----
    {
        const int w    = tid >> 6;    // 0..3 (one wave per route)
        const int lane = tid & 63;    // dims 2*lane, 2*lane+1
        const int* gi  = &s_idx[w * ROUTE_LEN];
        float2 m = make_float2(-INFINITY, -INFINITY);
        #pragma unroll 10
        for (int l = 0; l < ROUTE_LEN; ++l) {
            const float2 v = *reinterpret_cast<const float2*>(
                emb + (size_t)gi[l] * D_IN + lane * 2);
            m.x = fmaxf(m.x, v.x);
            m.y = fmaxf(m.y, v.y);
        }
        *reinterpret_cast<float2*>(&s_pooled[w][lane * 2]) = m;
    }
    __syncthreads();

    // ---- 3. GEMM + bias: thread tid computes output column tid for all RPB routes ----
    float h[RPB];
    {
        const float bo = bias[tid];
        #pragma unroll
        for (int r = 0; r < RPB; ++r) h[r] = bo;

        #pragma unroll 8
        for (int k = 0; k < D_IN; k += 4) {
            const float wk0 = W[(size_t)(k + 0) * D_OUT + tid];
            const float wk1 = W[(size_t)(k + 1) * D_OUT + tid];
            const float wk2 = W[(size_t)(k + 2) * D_OUT + tid];
            const float wk3 = W[(size_t)(k + 3) * D_OUT + tid];
            #pragma unroll
            for (int r = 0; r < RPB; ++r) {
                const float4 p = *reinterpret_cast<const float4*>(&s_pooled[r][k]);
                h[r] = fmaf(p.x, wk0, h[r]);
                h[r] = fmaf(p.y, wk1, h[r]);
                h[r] = fmaf(p.z, wk2, h[r]);
                h[r] = fmaf(p.w, wk3, h[r]);
            }
        }
    }

    // ---- 4. LayerNorm (E[x^2]-mu^2 form) + ReLU ----
    float s[RPB], ss[RPB];
    #pragma unroll
    for (int r = 0; r < RPB; ++r) { s[r] = h[r]; ss[r] = h[r] * h[r]; }

    #pragma unroll
    for (int off = 32; off > 0; off >>= 1) {
        #pragma unroll
        for (int r = 0; r < RPB; ++r) {
            s[r]  += __shfl_down(s[r],  off);
            ss[r] += __shfl_down(ss[r], off);
        }
    }
    const int wave = tid >> 6;
    if ((tid & 63) == 0) {
        #pragma unroll
        for (int r = 0; r < RPB; ++r) { s_sum[wave][r] = s[r]; s_ssq[wave][r] = ss[r]; }
    }
    __syncthreads();

    const float gm = gamma[tid];
    const float bt = beta[tid];
    #pragma unroll
    for (int r = 0; r < RPB; ++r) {
        const float tot = s_sum[0][r] + s_sum[1][r] + s_sum[2][r] + s_sum[3][r];
        const float tsq = s_ssq[0][r] + s_ssq[1][r] + s_ssq[2][r] + s_ssq[3][r];
        const float mu  = tot * (1.0f / D_OUT);
        const float var = tsq * (1.0f / D_OUT) - mu * mu;
        const float inv = rsqrtf(var + LN_EPS);
        const float y   = fmaxf((h[r] - mu) * inv * gm + bt, 0.0f);
        __builtin_nontemporal_store(y, &out[(size_t)(route0 + r) * D_OUT + tid]);
    }
}

extern "C" void kernel_launch(void* const* d_in, const int* in_sizes, int n_in,
                              void* d_out, int out_size, void* d_ws, size_t ws_size,
                              hipStream_t stream) {
    const float* emb   = (const float*)d_in[0];
    const int*   idx   = (const int*)  d_in[1];
    const float* W     = (const float*)d_in[2];
    const float* bias  = (const float*)d_in[3];
    const float* gamma = (const float*)d_in[4];
    const float* beta  = (const float*)d_in[5];
    float* out = (float*)d_out;

    routes_encoder_kernel<<<dim3(N_ROUTES / RPB), dim3(NTHREADS), 0, stream>>>(
        emb, idx, W, bias, gamma, beta, out);
}